// Round 1
// 374.676 us; speedup vs baseline: 1.0445x; 1.0445x over previous
//
#include <hip/hip_runtime.h>
#include <math.h>

#define NK 512
#define DD 256
#define NB 32
#define NT 4096

typedef __attribute__((ext_vector_type(8))) _Float16 f16x8;
typedef __attribute__((ext_vector_type(4))) float f32x4;

#define MARGIN 1.5e-4f
#define DCH 16      // d per chunk
#define NCH 16      // chunks (DD/DCH)
#define APAD 40     // shorts per LDS row (80 B: period-8 bank rotation, 2-way = free)

__device__ __forceinline__ unsigned short f16bits(float x) {
    _Float16 h = (_Float16)x;           // v_cvt_f16_f32, RNE
    unsigned short s;
    __builtin_memcpy(&s, &h, 2);
    return s;
}

// ---------------------------------------------------------------------------
// Prep: blocks 0..15 build Wpp (f16 w*4096, duplicated per-d slot pair);
// block 16 computes wsq (fp64 -> fp32 once) and zeroes the tie counter.
// Wpp layout: [(c*512 + k)*32] shorts, c = d-chunk, k = code (global 0..511).
// ---------------------------------------------------------------------------
__global__ __launch_bounds__(512) void prep_kernel(const float* __restrict__ W,
                                                   unsigned short* __restrict__ Wpp,
                                                   float* __restrict__ wsq,
                                                   int* __restrict__ gcnt) {
    const int bx = blockIdx.x;
    const int k  = threadIdx.x;   // 0..511
    if (bx < NCH) {
        const int d0 = bx * DCH;
        float w[16];
        const float4* src4 = (const float4*)(W + (size_t)k * DD + d0);
        #pragma unroll
        for (int q = 0; q < 4; ++q) {
            float4 v = src4[q];
            w[4 * q + 0] = v.x; w[4 * q + 1] = v.y; w[4 * q + 2] = v.z; w[4 * q + 3] = v.w;
        }
        __align__(16) unsigned int dw[16];
        #pragma unroll
        for (int j = 0; j < 16; ++j) {
            unsigned short s = f16bits(w[j] * 4096.0f);  // exact pow2 scale, then RNE
            dw[j] = (unsigned int)s | ((unsigned int)s << 16);  // (wh, wh) slot pair
        }
        unsigned short* dst = Wpp + ((size_t)bx * 512 + k) * 32;
        #pragma unroll
        for (int j = 0; j < 4; ++j) ((int4*)dst)[j] = ((const int4*)dw)[j];
    } else {
        const float4* row = (const float4*)(W + (size_t)k * DD);
        double s = 0.0;
        #pragma unroll 8
        for (int i = 0; i < DD / 4; ++i) {
            float4 v = row[i];
            s += (double)v.x * v.x + (double)v.y * v.y + (double)v.z * v.z + (double)v.w * v.w;
        }
        wsq[k] = (float)s;
        if (k == 0) *gcnt = 0;
    }
}

// ---------------------------------------------------------------------------
// Phase 1 (merged halves): block = 128 t x ALL 512 codes. 512 thr, 8 waves
// (mw = t-half, nw = k-quarter). Double-buffered LDS, ONE barrier per chunk,
// next-chunk global loads issued before the MFMA block (T14 split).
// Numerics identical to the validated 2-slot kernel (same quantization, same
// MFMA accumulation order, same fp32 rounding chain, same MARGIN).
// Writes out[] directly + appends near-ties to a global list.
// ---------------------------------------------------------------------------
__global__ __launch_bounds__(512, 2) void vq_phase1(const float* __restrict__ Z,
                                                    const unsigned short* __restrict__ Wpp,
                                                    const float* __restrict__ wsq,
                                                    int* __restrict__ out,
                                                    int* __restrict__ gties,
                                                    int* __restrict__ gcnt) {
    __shared__ __align__(16) short As[2][128 * APAD];   // 2 x 10240 B
    __shared__ __align__(16) short Bs[2][512 * APAD];   // 2 x 40960 B
    __shared__ double zred[512];                        // 4 KB
    __shared__ float  zf[128];
    __shared__ float  cb1[512], cb2[512];
    __shared__ int    cbi[512];
    __shared__ int    llist[128];
    __shared__ int    lcnt, gbase;

    const int tid  = threadIdx.x;
    const int wave = tid >> 6;
    const int lane = tid & 63;
    const int lm   = lane & 15;
    const int lq   = lane >> 4;
    const int mw   = wave & 1;   // t half (64 rows)
    const int nw   = wave >> 1;  // k quarter (128 codes)

    const int bx = blockIdx.x;
    const int b  = bx >> 5;
    const int t0 = (bx & 31) * 128;

    const int t_l = tid & 127;
    const int dg  = tid >> 7;    // 0..3, 4 d each per chunk

    const float* zcol = Z + (size_t)b * DD * NT + t0 + t_l;
    const unsigned short* wrow = Wpp + (size_t)tid * 32;   // code row = tid

    if (tid == 0) lcnt = 0;

    f32x4 acc[4][8];
    #pragma unroll
    for (int mt = 0; mt < 4; ++mt)
        #pragma unroll
        for (int nt = 0; nt < 8; ++nt)
            acc[mt][nt] = (f32x4){0.f, 0.f, 0.f, 0.f};

    double zacc = 0.0;

    // ---- prologue: stage chunk 0 into buf 0
    {
        float zv[4];
        #pragma unroll
        for (int j = 0; j < 4; ++j)
            zv[j] = zcol[(size_t)(dg * 4 + j) * NT];
        int4 wv[4];
        const int4* ws4 = (const int4*)wrow;
        #pragma unroll
        for (int q = 0; q < 4; ++q) wv[q] = ws4[q];

        #pragma unroll
        for (int j = 0; j < 4; ++j) zacc = fma((double)zv[j], (double)zv[j], zacc);
        __align__(16) unsigned int u[4];
        #pragma unroll
        for (int j = 0; j < 4; ++j) {
            _Float16 zh = (_Float16)zv[j];
            float rz = zv[j] - (float)zh;     // exact (Sterbenz)
            unsigned short hs, ls;
            __builtin_memcpy(&hs, &zh, 2);
            ls = f16bits(rz);
            u[j] = (unsigned int)hs | ((unsigned int)ls << 16);  // (zh, zl)
        }
        *(int4*)&As[0][t_l * APAD + dg * 8] = *(const int4*)u;
        int4* bd = (int4*)&Bs[0][tid * APAD];
        bd[0] = wv[0]; bd[1] = wv[1]; bd[2] = wv[2]; bd[3] = wv[3];
    }
    __syncthreads();

    for (int c = 0; c < NCH; ++c) {
        const int cur = c & 1;

        // ---- issue next chunk's global loads BEFORE compute (hide under MFMA)
        float zv2[4]; int4 wv2[4];
        if (c < NCH - 1) {
            const int d0 = (c + 1) * DCH;
            #pragma unroll
            for (int j = 0; j < 4; ++j)
                zv2[j] = zcol[(size_t)(d0 + dg * 4 + j) * NT];
            const int4* ws4 = (const int4*)(wrow + (size_t)(c + 1) * NK * 32);
            #pragma unroll
            for (int q = 0; q < 4; ++q) wv2[q] = ws4[q];
        }

        // ---- fragments + MFMA on buf[cur]
        f16x8 a[4], bb[8];
        #pragma unroll
        for (int mt = 0; mt < 4; ++mt)
            a[mt] = *(const f16x8*)&As[cur][(mw * 64 + mt * 16 + lm) * APAD + lq * 8];
        #pragma unroll
        for (int nt = 0; nt < 8; ++nt)
            bb[nt] = *(const f16x8*)&Bs[cur][(nw * 128 + nt * 16 + lm) * APAD + lq * 8];
        #pragma unroll
        for (int mt = 0; mt < 4; ++mt)
            #pragma unroll
            for (int nt = 0; nt < 8; ++nt)
                acc[mt][nt] = __builtin_amdgcn_mfma_f32_16x16x32_f16(
                    a[mt], bb[nt], acc[mt][nt], 0, 0, 0);

        // ---- convert + write buf[cur^1]; single barrier per chunk
        if (c < NCH - 1) {
            #pragma unroll
            for (int j = 0; j < 4; ++j) zacc = fma((double)zv2[j], (double)zv2[j], zacc);
            __align__(16) unsigned int u[4];
            #pragma unroll
            for (int j = 0; j < 4; ++j) {
                _Float16 zh = (_Float16)zv2[j];
                float rz = zv2[j] - (float)zh;
                unsigned short hs, ls;
                __builtin_memcpy(&hs, &zh, 2);
                ls = f16bits(rz);
                u[j] = (unsigned int)hs | ((unsigned int)ls << 16);
            }
            *(int4*)&As[cur ^ 1][t_l * APAD + dg * 8] = *(const int4*)u;
            int4* bd = (int4*)&Bs[cur ^ 1][tid * APAD];
            bd[0] = wv2[0]; bd[1] = wv2[1]; bd[2] = wv2[2]; bd[3] = wv2[3];
            __syncthreads();
        }
    }

    // ---- epilogue: zsq reduce (fp64 -> fp32 once), chain, per-t top-2
    zred[dg * 128 + t_l] = zacc;
    __syncthreads();
    if (tid < 128)
        zf[tid] = (float)(((zred[tid] + zred[128 + tid]) + zred[256 + tid]) + zred[384 + tid]);
    __syncthreads();

    float wq[8];
    #pragma unroll
    for (int nt = 0; nt < 8; ++nt)
        wq[nt] = wsq[nw * 128 + nt * 16 + lm];
    const int kbase = nw * 128 + lm;

    #pragma unroll
    for (int mt = 0; mt < 4; ++mt) {
        #pragma unroll
        for (int r = 0; r < 4; ++r) {
            float zz = zf[mw * 64 + mt * 16 + lq * 4 + r];
            float q1 = INFINITY, q2 = INFINITY;
            int i1 = 0x7fffffff;
            #pragma unroll
            for (int nt = 0; nt < 8; ++nt) {
                // acc holds cross*2^12; fl(2*cross) = acc * 2^-11 (exact pow2)
                float c2   = __fmul_rn(acc[mt][nt][r], 4.8828125e-4f);
                float dist = __fadd_rn(__fsub_rn(zz, c2), wq[nt]);
                int kk = kbase + nt * 16;
                if (dist < q1 || (dist == q1 && kk < i1)) { q2 = q1; q1 = dist; i1 = kk; }
                else if (dist < q2) q2 = dist;
            }
            #pragma unroll
            for (int mk = 1; mk <= 8; mk <<= 1) {
                float o1 = __shfl_xor(q1, mk);
                float o2 = __shfl_xor(q2, mk);
                int   oi = __shfl_xor(i1, mk);
                if (o1 < q1 || (o1 == q1 && oi < i1)) { q2 = fminf(q1, o2); q1 = o1; i1 = oi; }
                else { q2 = fminf(o1, q2); }
            }
            if (lm == 0) {
                int m = mw * 64 + mt * 16 + lq * 4 + r;
                cb1[m * 4 + nw] = q1;
                cb2[m * 4 + nw] = q2;
                cbi[m * 4 + nw] = i1;
            }
        }
    }
    __syncthreads();
    if (tid < 128) {
        float q1 = cb1[tid * 4], q2 = cb2[tid * 4];
        int   i1 = cbi[tid * 4];
        #pragma unroll
        for (int p = 1; p < 4; ++p) {
            float c1 = cb1[tid * 4 + p], c2v = cb2[tid * 4 + p];
            int   ci = cbi[tid * 4 + p];
            if (c1 < q1 || (c1 == q1 && ci < i1)) { q2 = fminf(q1, c2v); q1 = c1; i1 = ci; }
            else { q2 = fminf(q2, c1); }
        }
        out[(size_t)b * NT + t0 + tid] = i1;
        if (q2 - q1 <= MARGIN) {
            int p = atomicAdd(&lcnt, 1);
            llist[p] = b * NT + t0 + tid;       // global bt id
        }
    }
    __syncthreads();
    if (tid == 0) gbase = (lcnt > 0) ? atomicAdd(gcnt, lcnt) : 0;
    __syncthreads();
    if (tid < lcnt) gties[gbase + tid] = llist[tid];
}

// ---------------------------------------------------------------------------
// Tie fix: reads the global tie list; recomputes listed tokens exactly
// (identical fp32 chain / fmaf order as the validated kernel) in batches of 8.
// ---------------------------------------------------------------------------
__global__ __launch_bounds__(256) void vq_fix(const float* __restrict__ Z,
                                              const float* __restrict__ W,
                                              const float* __restrict__ wsq,
                                              const int* __restrict__ gties,
                                              const int* __restrict__ gcnt,
                                              int* __restrict__ out) {
    __shared__ __align__(16) float Zs[8][256];
    __shared__ double pz[8][32];
    __shared__ float  zsqs[8];
    __shared__ int    bts[8];
    __shared__ float  rv[8][4];
    __shared__ int    ri[8][4];

    const int tid  = threadIdx.x;
    const int lane = tid & 63;
    const int wvx  = tid >> 6;
    const int n    = *gcnt;

    for (int base = blockIdx.x * 8; base < n; base += (int)gridDim.x * 8) {
        const int m = (n - base < 8) ? (n - base) : 8;
        __syncthreads();
        if (tid < 8) bts[tid] = gties[base + ((tid < m) ? tid : 0)];
        __syncthreads();

        #pragma unroll
        for (int i = 0; i < 8; ++i) {
            if (i < m) {
                int tb = bts[i];
                int bb = tb >> 12, t = tb & 4095;
                Zs[i][tid] = Z[(size_t)bb * DD * NT + (size_t)tid * NT + t];
            }
        }
        __syncthreads();

        {
            int i = tid >> 5, seg = tid & 31;
            double s = 0.0;
            #pragma unroll
            for (int j = 0; j < 8; ++j) {
                double zz = (double)Zs[i][seg * 8 + j];
                s = fma(zz, zz, s);
            }
            pz[i][seg] = s;
        }
        __syncthreads();
        if (tid < 8) {
            double s = 0.0;
            #pragma unroll
            for (int j = 0; j < 32; ++j) s += pz[tid][j];
            zsqs[tid] = (float)s;
        }
        __syncthreads();

        float da[2][8];
        #pragma unroll
        for (int rr = 0; rr < 2; ++rr) {
            int k = tid + rr * 256;
            const float4* wr = (const float4*)(W + (size_t)k * DD);
            float a8[8];
            #pragma unroll
            for (int i = 0; i < 8; ++i) a8[i] = 0.f;
            #pragma unroll 2
            for (int q = 0; q < 64; ++q) {
                float4 w4 = wr[q];
                #pragma unroll
                for (int i = 0; i < 8; ++i) {
                    float4 z4 = *(const float4*)&Zs[i][4 * q];   // LDS broadcast
                    a8[i] = fmaf(z4.x, w4.x, a8[i]);
                    a8[i] = fmaf(z4.y, w4.y, a8[i]);
                    a8[i] = fmaf(z4.z, w4.z, a8[i]);
                    a8[i] = fmaf(z4.w, w4.w, a8[i]);
                }
            }
            float wqv = wsq[k];
            #pragma unroll
            for (int i = 0; i < 8; ++i)
                da[rr][i] = __fadd_rn(__fsub_rn(zsqs[i], __fmul_rn(2.0f, a8[i])), wqv);
        }

        #pragma unroll
        for (int i = 0; i < 8; ++i) {
            float v = da[0][i]; int ix = tid;
            if (da[1][i] < v) { v = da[1][i]; ix = tid + 256; }
            #pragma unroll
            for (int mk = 1; mk <= 32; mk <<= 1) {
                float ov = __shfl_xor(v, mk);
                int   oi = __shfl_xor(ix, mk);
                if (ov < v || (ov == v && oi < ix)) { v = ov; ix = oi; }
            }
            if (lane == 0) { rv[i][wvx] = v; ri[i][wvx] = ix; }
        }
        __syncthreads();
        if (tid < 8 && tid < m) {
            float v = INFINITY; int ix = 0x7fffffff;
            #pragma unroll
            for (int w = 0; w < 4; ++w) {
                if (rv[tid][w] < v || (rv[tid][w] == v && ri[tid][w] < ix)) {
                    v = rv[tid][w]; ix = ri[tid][w];
                }
            }
            out[bts[tid]] = ix;
        }
    }
}

// ---------------------------------------------------------------------------
// Fallback (R1 kernel) if ws is too small.
// ---------------------------------------------------------------------------
#define BT 128
#define BK 128
#define DCHUNK 32
#define NKC (NK / BK)
#define NDC (DD / DCHUNK)
#define WSTR (BK + 4)

__global__ __launch_bounds__(256) void vq_fallback(const float* __restrict__ Z,
                                                   const float* __restrict__ W,
                                                   int* __restrict__ out) {
    __shared__ __align__(16) float Zs[DCHUNK * BT];
    __shared__ __align__(16) float Ws[DCHUNK * WSTR];
    __shared__ float wsqs[NK];

    const int tid = threadIdx.x;
    const int tx  = tid & 15;
    const int ty  = tid >> 4;
    const int b   = blockIdx.y;
    const int t0  = blockIdx.x * BT;

    for (int k = tid; k < NK; k += 256) {
        const float4* row = (const float4*)(W + (size_t)k * DD);
        double s = 0.0;
        for (int i = 0; i < DD / 4; ++i) {
            float4 v = row[i];
            s += (double)v.x * v.x + (double)v.y * v.y + (double)v.z * v.z + (double)v.w * v.w;
        }
        wsqs[k] = (float)s;
    }

    const float* Zb = Z + (size_t)b * DD * NT + t0;

    float best[8]; int bidx[8];
    #pragma unroll
    for (int a = 0; a < 8; ++a) { best[a] = INFINITY; bidx[a] = 0x7fffffff; }
    double zsqd[8];
    #pragma unroll
    for (int a = 0; a < 8; ++a) zsqd[a] = 0.0;
    float zsqf[8];

    for (int kc = 0; kc < NKC; ++kc) {
        float acc[8][8];
        #pragma unroll
        for (int a = 0; a < 8; ++a)
            #pragma unroll
            for (int c = 0; c < 8; ++c) acc[a][c] = 0.f;

        for (int dc = 0; dc < NDC; ++dc) {
            const int d0 = dc * DCHUNK;
            __syncthreads();
            #pragma unroll
            for (int i = 0; i < 4; ++i) {
                int f  = tid + i * 256;
                int r  = f >> 5;
                int c4 = f & 31;
                float4 v = *(const float4*)(Zb + (size_t)(d0 + r) * NT + c4 * 4);
                *(float4*)(&Zs[r * BT + c4 * 4]) = v;
            }
            #pragma unroll
            for (int i = 0; i < 4; ++i) {
                int u  = tid + i * 256;
                int k  = u >> 3;
                int rg = u & 7;
                float4 v = *(const float4*)(W + (size_t)(kc * BK + k) * DD + d0 + rg * 4);
                Ws[(rg * 4 + 0) * WSTR + k] = v.x;
                Ws[(rg * 4 + 1) * WSTR + k] = v.y;
                Ws[(rg * 4 + 2) * WSTR + k] = v.z;
                Ws[(rg * 4 + 3) * WSTR + k] = v.w;
            }
            __syncthreads();
            #pragma unroll 4
            for (int d = 0; d < DCHUNK; ++d) {
                float4 z0 = *(const float4*)(&Zs[d * BT + ty * 8]);
                float4 z1 = *(const float4*)(&Zs[d * BT + ty * 8 + 4]);
                float4 w0 = *(const float4*)(&Ws[d * WSTR + tx * 8]);
                float4 w1 = *(const float4*)(&Ws[d * WSTR + tx * 8 + 4]);
                float za[8] = {z0.x, z0.y, z0.z, z0.w, z1.x, z1.y, z1.z, z1.w};
                float wa[8] = {w0.x, w0.y, w0.z, w0.w, w1.x, w1.y, w1.z, w1.w};
                if (kc == 0) {
                    #pragma unroll
                    for (int a = 0; a < 8; ++a)
                        zsqd[a] = fma((double)za[a], (double)za[a], zsqd[a]);
                }
                #pragma unroll
                for (int a = 0; a < 8; ++a)
                    #pragma unroll
                    for (int c = 0; c < 8; ++c)
                        acc[a][c] = fmaf(za[a], wa[c], acc[a][c]);
            }
        }
        if (kc == 0) {
            #pragma unroll
            for (int a = 0; a < 8; ++a) zsqf[a] = (float)zsqd[a];
        }
        #pragma unroll
        for (int c = 0; c < 8; ++c) {
            int   kg = kc * BK + tx * 8 + c;
            float wqv = wsqs[kg];
            #pragma unroll
            for (int a = 0; a < 8; ++a) {
                float c2   = __fmul_rn(2.0f, acc[a][c]);
                float s    = __fsub_rn(zsqf[a], c2);
                float dist = __fadd_rn(s, wqv);
                if (dist < best[a] || (dist == best[a] && kg < bidx[a])) {
                    best[a] = dist; bidx[a] = kg;
                }
            }
        }
    }
    __syncthreads();
    float* redv = Zs;
    int*   redi = (int*)Ws;
    #pragma unroll
    for (int a = 0; a < 8; ++a) {
        int tl2 = ty * 8 + a;
        redv[tl2 * 16 + tx] = best[a];
        redi[tl2 * 16 + tx] = bidx[a];
    }
    __syncthreads();
    if (tid < BT) {
        float bv = INFINITY; int bi = 0x7fffffff;
        #pragma unroll
        for (int j = 0; j < 16; ++j) {
            float v = redv[tid * 16 + j];
            int   i = redi[tid * 16 + j];
            if (v < bv || (v == bv && i < bi)) { bv = v; bi = i; }
        }
        out[(size_t)b * NT + t0 + tid] = bi;
    }
}

extern "C" void kernel_launch(void* const* d_in, const int* in_sizes, int n_in,
                              void* d_out, int out_size, void* d_ws, size_t ws_size,
                              hipStream_t stream) {
    const float* Z = (const float*)d_in[0];   // [B, D, T]
    const float* W = (const float*)d_in[1];   // [K, D]
    int* out = (int*)d_out;                   // [B, T]

    // ws layout
    const size_t OFF_WSQ = 0;                          // 512 f32
    const size_t OFF_CNT = 2048;                       // 1 int (tie counter)
    const size_t OFF_WPP = 4096;                       // 512 KB
    const size_t OFF_TIE = OFF_WPP + 524288;           // up to 131072 ints
    const size_t NEED    = OFF_TIE + 524288;           // 1,052,672 B

    if (ws_size >= NEED) {
        float* wsq = (float*)((char*)d_ws + OFF_WSQ);
        int*   gcnt = (int*)((char*)d_ws + OFF_CNT);
        unsigned short* wpp = (unsigned short*)((char*)d_ws + OFF_WPP);
        int*   gties = (int*)((char*)d_ws + OFF_TIE);

        prep_kernel<<<dim3(NCH + 1), dim3(512), 0, stream>>>(W, wpp, wsq, gcnt);
        vq_phase1<<<dim3(1024), dim3(512), 0, stream>>>(Z, wpp, wsq, out, gties, gcnt);
        vq_fix<<<dim3(256), dim3(256), 0, stream>>>(Z, W, wsq, gties, gcnt, out);
    } else {
        vq_fallback<<<dim3(NT / BT, NB), dim3(256), 0, stream>>>(Z, W, out);
    }
}

// Round 2
// 340.266 us; speedup vs baseline: 1.1502x; 1.1011x over previous
//
#include <hip/hip_runtime.h>
#include <math.h>

#define NK 512
#define DD 256
#define NB 32
#define NT 4096

typedef __attribute__((ext_vector_type(8))) _Float16 f16x8;
typedef __attribute__((ext_vector_type(4))) float f32x4;

#define MARGIN 1.5e-4f
#define DCH 16      // d per chunk
#define NCH 16      // chunks (DD/DCH)
#define ASTR 536    // shorts per A row (1072 B; 268 dw, 268%32=12 -> period-8 bank rotation)

__device__ __forceinline__ unsigned short f16bits(float x) {
    _Float16 h = (_Float16)x;           // v_cvt_f16_f32, RNE
    unsigned short s;
    __builtin_memcpy(&s, &h, 2);
    return s;
}

// ---------------------------------------------------------------------------
// Prep: blocks 0..15 build Wpp (f16 w*4096, duplicated per-d slot pair);
// block 16 computes wsq (fp64 -> fp32 once) and zeroes the tie counter.
// Wpp layout: [(c*512 + k)*32] shorts, c = d-chunk, k = code (global 0..511).
// ---------------------------------------------------------------------------
__global__ __launch_bounds__(512) void prep_kernel(const float* __restrict__ W,
                                                   unsigned short* __restrict__ Wpp,
                                                   float* __restrict__ wsq,
                                                   int* __restrict__ gcnt) {
    const int bx = blockIdx.x;
    const int k  = threadIdx.x;   // 0..511
    if (bx < NCH) {
        const int d0 = bx * DCH;
        float w[16];
        const float4* src4 = (const float4*)(W + (size_t)k * DD + d0);
        #pragma unroll
        for (int q = 0; q < 4; ++q) {
            float4 v = src4[q];
            w[4 * q + 0] = v.x; w[4 * q + 1] = v.y; w[4 * q + 2] = v.z; w[4 * q + 3] = v.w;
        }
        __align__(16) unsigned int dw[16];
        #pragma unroll
        for (int j = 0; j < 16; ++j) {
            unsigned short s = f16bits(w[j] * 4096.0f);  // exact pow2 scale, then RNE
            dw[j] = (unsigned int)s | ((unsigned int)s << 16);  // (wh, wh) slot pair
        }
        unsigned short* dst = Wpp + ((size_t)bx * 512 + k) * 32;
        #pragma unroll
        for (int j = 0; j < 4; ++j) ((int4*)dst)[j] = ((const int4*)dw)[j];
    } else {
        const float4* row = (const float4*)(W + (size_t)k * DD);
        double s = 0.0;
        #pragma unroll 8
        for (int i = 0; i < DD / 4; ++i) {
            float4 v = row[i];
            s += (double)v.x * v.x + (double)v.y * v.y + (double)v.z * v.z + (double)v.w * v.w;
        }
        wsq[k] = (float)s;
        if (k == 0) *gcnt = 0;
    }
}

// ---------------------------------------------------------------------------
// Phase 1, barrier-free main loop: block = 64 t x ALL 512 codes, 256 thr,
// 4 waves (nw = k-quarter of 128 codes each; per wave 64t x 128c, acc[4][8]).
// A (z, split-f16) staged ONCE in LDS (64 x ASTR shorts, 68.6 KB -> 2 blk/CU).
// B (Wpp) read directly from global L2 into registers, depth-1 prefetch,
// counted vmcnt, ZERO __syncthreads in the 16-chunk loop.
// Numerics identical to the validated kernel (same f16 split, same Wpp bytes,
// same per-chunk MFMA accumulation order, same fp32 rounding chain, MARGIN).
// ---------------------------------------------------------------------------
__global__ __launch_bounds__(256, 2) void vq_phase1(const float* __restrict__ Z,
                                                    const unsigned short* __restrict__ Wpp,
                                                    const float* __restrict__ wsq,
                                                    int* __restrict__ out,
                                                    int* __restrict__ gties,
                                                    int* __restrict__ gcnt) {
    __shared__ __align__(16) short As[64 * ASTR];   // 68,608 B
    __shared__ int lcnt, gbase;

    const int tid  = threadIdx.x;
    const int wave = tid >> 6;
    const int lane = tid & 63;
    const int lm   = lane & 15;
    const int lq   = lane >> 4;
    const int nw   = wave;        // k quarter (128 codes)

    const int bx = blockIdx.x;
    const int b  = bx >> 6;
    const int t0 = (bx & 63) * 64;

    const int t_l = tid & 63;
    const int dgs = tid >> 6;     // 0..3, 64 d each

    const float* zcol = Z + (size_t)b * DD * NT + t0 + t_l;

    if (tid == 0) lcnt = 0;

    // ---- stage ALL of A (64 t x 256 d, split-f16) + fp64 zsq partials
    double zacc = 0.0;
    #pragma unroll
    for (int half = 0; half < 2; ++half) {
        float zv[32];
        #pragma unroll
        for (int j = 0; j < 32; ++j)
            zv[j] = zcol[(size_t)(dgs * 64 + half * 32 + j) * NT];
        #pragma unroll
        for (int j = 0; j < 32; ++j)
            zacc = fma((double)zv[j], (double)zv[j], zacc);
        #pragma unroll
        for (int j0 = 0; j0 < 32; j0 += 4) {
            __align__(16) unsigned int u[4];
            #pragma unroll
            for (int q = 0; q < 4; ++q) {
                float z = zv[j0 + q];
                _Float16 zh = (_Float16)z;
                float rz = z - (float)zh;     // exact (Sterbenz)
                unsigned short hs, ls;
                __builtin_memcpy(&hs, &zh, 2);
                ls = f16bits(rz);
                u[q] = (unsigned int)hs | ((unsigned int)ls << 16);  // (zh, zl)
            }
            // shorts: As[t_l*ASTR + (dgs*64 + half*32 + j0)*2]
            *(int4*)&As[t_l * ASTR + (dgs * 64 + half * 32 + j0) * 2] = *(const int4*)u;
        }
    }
    __syncthreads();   // the ONLY pre-epilogue barrier

    // ---- B fragment base: lane reads 16 B of code (nw*128 + nt*16 + lm)
    const unsigned short* wb = Wpp + ((size_t)(nw * 128 + lm) * 32) + lq * 8;

    f32x4 acc[4][8];
    #pragma unroll
    for (int mt = 0; mt < 4; ++mt)
        #pragma unroll
        for (int nt = 0; nt < 8; ++nt)
            acc[mt][nt] = (f32x4){0.f, 0.f, 0.f, 0.f};

    int4 bv0[8], bv1[8];
    #pragma unroll
    for (int nt = 0; nt < 8; ++nt)
        bv0[nt] = *(const int4*)(wb + nt * 512);

    #pragma unroll
    for (int c = 0; c < NCH; ++c) {
        int4* cur = (c & 1) ? bv1 : bv0;
        int4* nxt = (c & 1) ? bv0 : bv1;
        // prefetch next chunk's B frags (stay in flight across the MFMAs)
        if (c < NCH - 1) {
            const unsigned short* wp = wb + (size_t)(c + 1) * 16384;
            #pragma unroll
            for (int nt = 0; nt < 8; ++nt)
                nxt[nt] = *(const int4*)(wp + nt * 512);
        }
        f16x8 a[4];
        #pragma unroll
        for (int mt = 0; mt < 4; ++mt)
            a[mt] = *(const f16x8*)&As[(mt * 16 + lm) * ASTR + c * 32 + lq * 8];
        #pragma unroll
        for (int mt = 0; mt < 4; ++mt)
            #pragma unroll
            for (int nt = 0; nt < 8; ++nt)
                acc[mt][nt] = __builtin_amdgcn_mfma_f32_16x16x32_f16(
                    a[mt], *(const f16x8*)&cur[nt], acc[mt][nt], 0, 0, 0);
    }

    // ---- epilogue: zsq reduce (fp64 -> fp32 once), chain, per-t top-2
    __syncthreads();                       // all A reads done; reuse As
    double* zred = (double*)As;            // [4][64]
    float*  zf   = (float*)(As + 1024);    // 64 f32
    float*  cb1  = (float*)(As + 1536);    // [64][4]
    float*  cb2  = (float*)(As + 2048);
    int*    cbi  = (int*)(As + 2560);
    int*    llist = (int*)(As + 3072);     // 64 ints

    zred[dgs * 64 + t_l] = zacc;
    __syncthreads();
    if (tid < 64) {
        double s = zred[tid];
        #pragma unroll
        for (int p = 1; p < 4; ++p) s += zred[p * 64 + tid];
        zf[tid] = (float)s;
    }
    __syncthreads();

    float wq[8];
    #pragma unroll
    for (int nt = 0; nt < 8; ++nt)
        wq[nt] = wsq[nw * 128 + nt * 16 + lm];
    const int kbase = nw * 128 + lm;

    #pragma unroll
    for (int mt = 0; mt < 4; ++mt) {
        #pragma unroll
        for (int r = 0; r < 4; ++r) {
            float zz = zf[mt * 16 + lq * 4 + r];
            float q1 = INFINITY, q2 = INFINITY;
            int i1 = 0x7fffffff;
            #pragma unroll
            for (int nt = 0; nt < 8; ++nt) {
                // acc holds cross*2^12; fl(2*cross) = acc * 2^-11 (exact pow2)
                float c2   = __fmul_rn(acc[mt][nt][r], 4.8828125e-4f);
                float dist = __fadd_rn(__fsub_rn(zz, c2), wq[nt]);
                int kk = kbase + nt * 16;
                if (dist < q1 || (dist == q1 && kk < i1)) { q2 = q1; q1 = dist; i1 = kk; }
                else if (dist < q2) q2 = dist;
            }
            #pragma unroll
            for (int mk = 1; mk <= 8; mk <<= 1) {
                float o1 = __shfl_xor(q1, mk);
                float o2 = __shfl_xor(q2, mk);
                int   oi = __shfl_xor(i1, mk);
                if (o1 < q1 || (o1 == q1 && oi < i1)) { q2 = fminf(q1, o2); q1 = o1; i1 = oi; }
                else { q2 = fminf(o1, q2); }
            }
            if (lm == 0) {
                int m = mt * 16 + lq * 4 + r;
                cb1[m * 4 + nw] = q1;
                cb2[m * 4 + nw] = q2;
                cbi[m * 4 + nw] = i1;
            }
        }
    }
    __syncthreads();
    if (tid < 64) {
        float q1 = cb1[tid * 4], q2 = cb2[tid * 4];
        int   i1 = cbi[tid * 4];
        #pragma unroll
        for (int p = 1; p < 4; ++p) {
            float c1 = cb1[tid * 4 + p], c2v = cb2[tid * 4 + p];
            int   ci = cbi[tid * 4 + p];
            if (c1 < q1 || (c1 == q1 && ci < i1)) { q2 = fminf(q1, c2v); q1 = c1; i1 = ci; }
            else { q2 = fminf(q2, c1); }
        }
        out[(size_t)b * NT + t0 + tid] = i1;
        if (q2 - q1 <= MARGIN) {
            int p = atomicAdd(&lcnt, 1);
            llist[p] = b * NT + t0 + tid;       // global bt id
        }
    }
    __syncthreads();
    if (tid == 0) gbase = (lcnt > 0) ? atomicAdd(gcnt, lcnt) : 0;
    __syncthreads();
    if (tid < lcnt) gties[gbase + tid] = llist[tid];
}

// ---------------------------------------------------------------------------
// Tie fix: reads the global tie list; recomputes listed tokens exactly
// (identical fp32 chain / fmaf order as the validated kernel) in batches of 8.
// ---------------------------------------------------------------------------
__global__ __launch_bounds__(256) void vq_fix(const float* __restrict__ Z,
                                              const float* __restrict__ W,
                                              const float* __restrict__ wsq,
                                              const int* __restrict__ gties,
                                              const int* __restrict__ gcnt,
                                              int* __restrict__ out) {
    __shared__ __align__(16) float Zs[8][256];
    __shared__ double pz[8][32];
    __shared__ float  zsqs[8];
    __shared__ int    bts[8];
    __shared__ float  rv[8][4];
    __shared__ int    ri[8][4];

    const int tid  = threadIdx.x;
    const int lane = tid & 63;
    const int wvx  = tid >> 6;
    const int n    = *gcnt;

    for (int base = blockIdx.x * 8; base < n; base += (int)gridDim.x * 8) {
        const int m = (n - base < 8) ? (n - base) : 8;
        __syncthreads();
        if (tid < 8) bts[tid] = gties[base + ((tid < m) ? tid : 0)];
        __syncthreads();

        #pragma unroll
        for (int i = 0; i < 8; ++i) {
            if (i < m) {
                int tb = bts[i];
                int bb = tb >> 12, t = tb & 4095;
                Zs[i][tid] = Z[(size_t)bb * DD * NT + (size_t)tid * NT + t];
            }
        }
        __syncthreads();

        {
            int i = tid >> 5, seg = tid & 31;
            double s = 0.0;
            #pragma unroll
            for (int j = 0; j < 8; ++j) {
                double zz = (double)Zs[i][seg * 8 + j];
                s = fma(zz, zz, s);
            }
            pz[i][seg] = s;
        }
        __syncthreads();
        if (tid < 8) {
            double s = 0.0;
            #pragma unroll
            for (int j = 0; j < 32; ++j) s += pz[tid][j];
            zsqs[tid] = (float)s;
        }
        __syncthreads();

        float da[2][8];
        #pragma unroll
        for (int rr = 0; rr < 2; ++rr) {
            int k = tid + rr * 256;
            const float4* wr = (const float4*)(W + (size_t)k * DD);
            float a8[8];
            #pragma unroll
            for (int i = 0; i < 8; ++i) a8[i] = 0.f;
            #pragma unroll 2
            for (int q = 0; q < 64; ++q) {
                float4 w4 = wr[q];
                #pragma unroll
                for (int i = 0; i < 8; ++i) {
                    float4 z4 = *(const float4*)&Zs[i][4 * q];   // LDS broadcast
                    a8[i] = fmaf(z4.x, w4.x, a8[i]);
                    a8[i] = fmaf(z4.y, w4.y, a8[i]);
                    a8[i] = fmaf(z4.z, w4.z, a8[i]);
                    a8[i] = fmaf(z4.w, w4.w, a8[i]);
                }
            }
            float wqv = wsq[k];
            #pragma unroll
            for (int i = 0; i < 8; ++i)
                da[rr][i] = __fadd_rn(__fsub_rn(zsqs[i], __fmul_rn(2.0f, a8[i])), wqv);
        }

        #pragma unroll
        for (int i = 0; i < 8; ++i) {
            float v = da[0][i]; int ix = tid;
            if (da[1][i] < v) { v = da[1][i]; ix = tid + 256; }
            #pragma unroll
            for (int mk = 1; mk <= 32; mk <<= 1) {
                float ov = __shfl_xor(v, mk);
                int   oi = __shfl_xor(ix, mk);
                if (ov < v || (ov == v && oi < ix)) { v = ov; ix = oi; }
            }
            if (lane == 0) { rv[i][wvx] = v; ri[i][wvx] = ix; }
        }
        __syncthreads();
        if (tid < 8 && tid < m) {
            float v = INFINITY; int ix = 0x7fffffff;
            #pragma unroll
            for (int w = 0; w < 4; ++w) {
                if (rv[tid][w] < v || (rv[tid][w] == v && ri[tid][w] < ix)) {
                    v = rv[tid][w]; ix = ri[tid][w];
                }
            }
            out[bts[tid]] = ix;
        }
    }
}

// ---------------------------------------------------------------------------
// Fallback (R1 kernel) if ws is too small.
// ---------------------------------------------------------------------------
#define BT 128
#define BK 128
#define DCHUNK 32
#define NKC (NK / BK)
#define NDC (DD / DCHUNK)
#define WSTR (BK + 4)

__global__ __launch_bounds__(256) void vq_fallback(const float* __restrict__ Z,
                                                   const float* __restrict__ W,
                                                   int* __restrict__ out) {
    __shared__ __align__(16) float Zs[DCHUNK * BT];
    __shared__ __align__(16) float Ws[DCHUNK * WSTR];
    __shared__ float wsqs[NK];

    const int tid = threadIdx.x;
    const int tx  = tid & 15;
    const int ty  = tid >> 4;
    const int b   = blockIdx.y;
    const int t0  = blockIdx.x * BT;

    for (int k = tid; k < NK; k += 256) {
        const float4* row = (const float4*)(W + (size_t)k * DD);
        double s = 0.0;
        for (int i = 0; i < DD / 4; ++i) {
            float4 v = row[i];
            s += (double)v.x * v.x + (double)v.y * v.y + (double)v.z * v.z + (double)v.w * v.w;
        }
        wsqs[k] = (float)s;
    }

    const float* Zb = Z + (size_t)b * DD * NT + t0;

    float best[8]; int bidx[8];
    #pragma unroll
    for (int a = 0; a < 8; ++a) { best[a] = INFINITY; bidx[a] = 0x7fffffff; }
    double zsqd[8];
    #pragma unroll
    for (int a = 0; a < 8; ++a) zsqd[a] = 0.0;
    float zsqf[8];

    for (int kc = 0; kc < NKC; ++kc) {
        float acc[8][8];
        #pragma unroll
        for (int a = 0; a < 8; ++a)
            #pragma unroll
            for (int c = 0; c < 8; ++c) acc[a][c] = 0.f;

        for (int dc = 0; dc < NDC; ++dc) {
            const int d0 = dc * DCHUNK;
            __syncthreads();
            #pragma unroll
            for (int i = 0; i < 4; ++i) {
                int f  = tid + i * 256;
                int r  = f >> 5;
                int c4 = f & 31;
                float4 v = *(const float4*)(Zb + (size_t)(d0 + r) * NT + c4 * 4);
                *(float4*)(&Zs[r * BT + c4 * 4]) = v;
            }
            #pragma unroll
            for (int i = 0; i < 4; ++i) {
                int u  = tid + i * 256;
                int k  = u >> 3;
                int rg = u & 7;
                float4 v = *(const float4*)(W + (size_t)(kc * BK + k) * DD + d0 + rg * 4);
                Ws[(rg * 4 + 0) * WSTR + k] = v.x;
                Ws[(rg * 4 + 1) * WSTR + k] = v.y;
                Ws[(rg * 4 + 2) * WSTR + k] = v.z;
                Ws[(rg * 4 + 3) * WSTR + k] = v.w;
            }
            __syncthreads();
            #pragma unroll 4
            for (int d = 0; d < DCHUNK; ++d) {
                float4 z0 = *(const float4*)(&Zs[d * BT + ty * 8]);
                float4 z1 = *(const float4*)(&Zs[d * BT + ty * 8 + 4]);
                float4 w0 = *(const float4*)(&Ws[d * WSTR + tx * 8]);
                float4 w1 = *(const float4*)(&Ws[d * WSTR + tx * 8 + 4]);
                float za[8] = {z0.x, z0.y, z0.z, z0.w, z1.x, z1.y, z1.z, z1.w};
                float wa[8] = {w0.x, w0.y, w0.z, w0.w, w1.x, w1.y, w1.z, w1.w};
                if (kc == 0) {
                    #pragma unroll
                    for (int a = 0; a < 8; ++a)
                        zsqd[a] = fma((double)za[a], (double)za[a], zsqd[a]);
                }
                #pragma unroll
                for (int a = 0; a < 8; ++a)
                    #pragma unroll
                    for (int c = 0; c < 8; ++c)
                        acc[a][c] = fmaf(za[a], wa[c], acc[a][c]);
            }
        }
        if (kc == 0) {
            #pragma unroll
            for (int a = 0; a < 8; ++a) zsqf[a] = (float)zsqd[a];
        }
        #pragma unroll
        for (int c = 0; c < 8; ++c) {
            int   kg = kc * BK + tx * 8 + c;
            float wqv = wsqs[kg];
            #pragma unroll
            for (int a = 0; a < 8; ++a) {
                float c2   = __fmul_rn(2.0f, acc[a][c]);
                float s    = __fsub_rn(zsqf[a], c2);
                float dist = __fadd_rn(s, wqv);
                if (dist < best[a] || (dist == best[a] && kg < bidx[a])) {
                    best[a] = dist; bidx[a] = kg;
                }
            }
        }
    }
    __syncthreads();
    float* redv = Zs;
    int*   redi = (int*)Ws;
    #pragma unroll
    for (int a = 0; a < 8; ++a) {
        int tl2 = ty * 8 + a;
        redv[tl2 * 16 + tx] = best[a];
        redi[tl2 * 16 + tx] = bidx[a];
    }
    __syncthreads();
    if (tid < BT) {
        float bv = INFINITY; int bi = 0x7fffffff;
        #pragma unroll
        for (int j = 0; j < 16; ++j) {
            float v = redv[tid * 16 + j];
            int   i = redi[tid * 16 + j];
            if (v < bv || (v == bv && i < bi)) { bv = v; bi = i; }
        }
        out[(size_t)b * NT + t0 + tid] = bi;
    }
}

extern "C" void kernel_launch(void* const* d_in, const int* in_sizes, int n_in,
                              void* d_out, int out_size, void* d_ws, size_t ws_size,
                              hipStream_t stream) {
    const float* Z = (const float*)d_in[0];   // [B, D, T]
    const float* W = (const float*)d_in[1];   // [K, D]
    int* out = (int*)d_out;                   // [B, T]

    // ws layout
    const size_t OFF_WSQ = 0;                          // 512 f32
    const size_t OFF_CNT = 2048;                       // 1 int (tie counter)
    const size_t OFF_WPP = 4096;                       // 512 KB
    const size_t OFF_TIE = OFF_WPP + 524288;           // up to 131072 ints
    const size_t NEED    = OFF_TIE + 524288;           // 1,052,672 B

    if (ws_size >= NEED) {
        float* wsq = (float*)((char*)d_ws + OFF_WSQ);
        int*   gcnt = (int*)((char*)d_ws + OFF_CNT);
        unsigned short* wpp = (unsigned short*)((char*)d_ws + OFF_WPP);
        int*   gties = (int*)((char*)d_ws + OFF_TIE);

        prep_kernel<<<dim3(NCH + 1), dim3(512), 0, stream>>>(W, wpp, wsq, gcnt);
        vq_phase1<<<dim3(2048), dim3(256), 0, stream>>>(Z, wpp, wsq, out, gties, gcnt);
        vq_fix<<<dim3(256), dim3(256), 0, stream>>>(Z, W, wsq, gties, gcnt, out);
    } else {
        vq_fallback<<<dim3(NT / BT, NB), dim3(256), 0, stream>>>(Z, W, out);
    }
}